// Round 10
// baseline (1377.658 us; speedup 1.0000x reference)
//
#include <hip/hip_runtime.h>
#include <hip/hip_fp16.h>

#define BB 16
#define NN 1024
#define DD 256

typedef _Float16 h8 __attribute__((ext_vector_type(8)));
typedef _Float16 hv4 __attribute__((ext_vector_type(4)));
typedef float f32x4 __attribute__((ext_vector_type(4)));

#if __has_builtin(__builtin_amdgcn_exp2f)
#define EXP2F(x) __builtin_amdgcn_exp2f(x)
#else
#define EXP2F(x) exp2f(x)
#endif
#if __has_builtin(__builtin_amdgcn_logf)
#define LOG2F(x) __builtin_amdgcn_logf(x)
#else
#define LOG2F(x) log2f(x)
#endif

// log2-domain: A2s = -100*log2e*relu(1-S) - CPOS2*|i-j|   (pos prior folded in, fp16)
constexpr float K_A2  = -144.26950408889634f;                 // -100*log2(e)
constexpr float CPOS2 = (float)(0.2 * 1.4426950408889634 / 1023.0);
constexpr float C1    = 0.06931471805599453f;                 // ln2/10
constexpr float BASE2 = -10.0f;                               // log2(1/1024 + 1e-12)

#define PIDX(i) ((i) + ((i) >> 3))

__device__ __forceinline__ float waveReduceSum(float v) {
#pragma unroll
  for (int o = 32; o; o >>= 1) v += __shfl_xor(v, o);
  return v;
}

__device__ __forceinline__ void ldsVec16p(const float* lds, int j0, float (&out)[16]) {
#pragma unroll
  for (int k = 0; k < 8; ++k) {
    out[k] = lds[PIDX(j0 + k)];
    out[8 + k] = lds[PIDX(512 + j0 + k)];
  }
}

__device__ __forceinline__ float lseRow(const h8 (&rw)[2], const float (&gv)[16]) {
  float x[16];
#pragma unroll
  for (int k = 0; k < 8; ++k) {
    x[k]     = (float)rw[0][k] + gv[k];
    x[8 + k] = (float)rw[1][k] + gv[8 + k];
  }
  float m = x[0];
#pragma unroll
  for (int k = 1; k < 16; ++k) m = fmaxf(m, x[k]);
#pragma unroll
  for (int o = 32; o; o >>= 1) m = fmaxf(m, __shfl_xor(m, o));
  float s = 0.f;
#pragma unroll
  for (int k = 0; k < 16; ++k) s += EXP2F(x[k] - m);
  s = waveReduceSum(s);
  return BASE2 - (m + LOG2F(s));
}

// uncached 8B store (to coherent point) for cross-XCD partials
__device__ __forceinline__ void st2_cv(float* p, float a, float b) {
  float2 q = {a, b};
  asm volatile("global_store_dwordx2 %0, %1, off sc0 sc1" :: "v"(p), "v"(q) : "memory");
}

// ---------------- K1: normalize rows of X and Y -> fp16 ----------------
__global__ __launch_bounds__(256) void normalize_kernel(
    const float* __restrict__ X, const float* __restrict__ Y,
    _Float16* __restrict__ Xh, _Float16* __restrict__ Yh) {
  int wave = threadIdx.x >> 6;
  int lane = threadIdx.x & 63;
  int row = blockIdx.x * 4 + wave;
  const float* src;
  _Float16* dst;
  if (row < BB * NN) { src = X + (size_t)row * DD; dst = Xh + (size_t)row * DD; }
  else { int r2 = row - BB * NN; src = Y + (size_t)r2 * DD; dst = Yh + (size_t)r2 * DD; }
  float4 v = *(const float4*)(src + lane * 4);
  float ss = v.x * v.x + v.y * v.y + v.z * v.z + v.w * v.w;
  ss = waveReduceSum(ss);
  float sc = 1.0f / fmaxf(sqrtf(ss), 1e-12f);
  hv4 hv;
  hv[0] = (_Float16)(v.x * sc); hv[1] = (_Float16)(v.y * sc);
  hv[2] = (_Float16)(v.z * sc); hv[3] = (_Float16)(v.w * sc);
  *(hv4*)(dst + lane * 4) = hv;
}

// ---------------- K1b: tiled transpose X,Y -> fp16 [b][d][n] ----------------
__global__ __launch_bounds__(256) void transpose_kernel(
    const float* __restrict__ X, const float* __restrict__ Y,
    _Float16* __restrict__ XT, _Float16* __restrict__ YT) {
  __shared__ _Float16 tile[64][72];
  int zb = blockIdx.z;
  const float* E;
  _Float16* ET;
  if (zb < BB) { E = X + (size_t)zb * NN * DD; ET = XT + (size_t)zb * DD * NN; }
  else { E = Y + (size_t)(zb - BB) * NN * DD; ET = YT + (size_t)(zb - BB) * DD * NN; }
  int n0 = blockIdx.x * 64, d0 = blockIdx.y * 64;
  int t = threadIdx.x;
  int lr = t >> 2, lc = (t & 3) * 16;
#pragma unroll
  for (int k = 0; k < 16; k += 4) {
    float4 v = *(const float4*)(E + (size_t)(n0 + lr) * DD + d0 + lc + k);
    tile[lc + k + 0][lr] = (_Float16)v.x;
    tile[lc + k + 1][lr] = (_Float16)v.y;
    tile[lc + k + 2][lr] = (_Float16)v.z;
    tile[lc + k + 3][lr] = (_Float16)v.w;
  }
  __syncthreads();
#pragma unroll
  for (int k = 0; k < 16; k += 8) {
    h8 o;
#pragma unroll
    for (int j = 0; j < 8; ++j) o[j] = tile[lr][lc + k + j];
    *(h8*)(ET + (size_t)(d0 + lr) * NN + n0 + lc + k) = o;
  }
}

// ---------------- K2: both S-gemms in one dispatch (z = dir*16 + b) ----------
__global__ __launch_bounds__(256) void gemm_a2_kernel(
    const _Float16* __restrict__ Xh, const _Float16* __restrict__ Yh,
    _Float16* __restrict__ A2, _Float16* __restrict__ A2T) {
  const int zb = blockIdx.z;
  const int b = zb & 15;
  const _Float16* Ah = (zb < BB) ? Xh : Yh;
  const _Float16* Bh = (zb < BB) ? Yh : Xh;
  _Float16* Out = (zb < BB) ? A2 : A2T;
  const int I0 = blockIdx.y * 128;
  const int J0 = blockIdx.x * 128;
  const int lane = threadIdx.x & 63;
  const int wave = threadIdx.x >> 6;
  const int m = lane & 15, quad = lane >> 4;
  const _Float16* Abase = Ah + ((size_t)b * NN + I0 + wave * 32) * DD;
  const _Float16* Bbase = Bh + ((size_t)b * NN + J0) * DD;
  f32x4 acc[2][8] = {};
  for (int k0 = 0; k0 < DD; k0 += 32) {
    int koff = k0 + quad * 8;
    h8 a0 = *(const h8*)(Abase + (size_t)m * DD + koff);
    h8 a1 = *(const h8*)(Abase + (size_t)(m + 16) * DD + koff);
#pragma unroll
    for (int t = 0; t < 8; ++t) {
      h8 bf = *(const h8*)(Bbase + (size_t)(t * 16 + m) * DD + koff);
      acc[0][t] = __builtin_amdgcn_mfma_f32_16x16x32_f16(a0, bf, acc[0][t], 0, 0, 0);
      acc[1][t] = __builtin_amdgcn_mfma_f32_16x16x32_f16(a1, bf, acc[1][t], 0, 0, 0);
    }
  }
  _Float16* Ob = Out + ((size_t)b * NN + I0 + wave * 32) * NN + J0;
#pragma unroll
  for (int a = 0; a < 2; ++a)
#pragma unroll
    for (int t = 0; t < 8; ++t)
#pragma unroll
      for (int r = 0; r < 4; ++r) {
        int row = a * 16 + quad * 4 + r;
        int col = t * 16 + m;
        float s = acc[a][t][r];
        float ri = (float)(I0 + wave * 32 + row);
        float ci = (float)(J0 + col);
        Ob[(size_t)row * NN + col] =
            (_Float16)(K_A2 * fmaxf(1.0f - s, 0.0f) - CPOS2 * fabsf(ri - ci));
      }
}

// ---------------- K3: ONE full sinkhorn iteration per dispatch ----------------
// Block (slab, b): 32 rows of A2. Pass A: f_i = BASE2 - lse_j(a2+g) for own rows.
// Pass B: partial column-lse (m_j,s_j) over own slab using own fresh f -> uncached
// contiguous stores to the coherent point. Fire-and-forget tail: last-arriving
// block per batch (plain atomicAdd counter, nobody waits) combines 32 partials
// per column into g_out (plain cached loads are safe: dispatch-start invalidate +
// no prior cached reads of partials; cached g_out store is written back at
// dispatch end). g double-buffered across iterations (late-block safety).
__global__ __launch_bounds__(512) void sink_iter_kernel(
    const _Float16* __restrict__ A2, const float* __restrict__ gin,
    float* __restrict__ gout, float* __restrict__ Fv,
    float* __restrict__ partials, unsigned* __restrict__ cnt) {
  __shared__ float lv[NN + NN / 8];
  __shared__ float f_l[32];
  __shared__ int isLast;
  const int b = blockIdx.y;
  const int slab = blockIdx.x;                  // 0..31
  const int t = threadIdx.x, lane = t & 63, wave = t >> 6;   // 8 waves
  // stage g
  float2 gsv = *(const float2*)(gin + b * NN + 2 * t);
  lv[PIDX(2 * t)] = gsv.x;
  lv[PIDX(2 * t + 1)] = gsv.y;
  __syncthreads();
  const int j0 = lane * 8;
  float gv[16];
  ldsVec16p(lv, j0, gv);
  const _Float16* Pb = A2 + (size_t)b * NN * NN;
  const int r0 = slab * 32 + wave * 4;
  // pass A: 4 rows per wave
#pragma unroll
  for (int r = 0; r < 4; ++r) {
    h8 q[2];
    q[0] = *(const h8*)(Pb + (size_t)(r0 + r) * NN + j0);
    q[1] = *(const h8*)(Pb + (size_t)(r0 + r) * NN + 512 + j0);
    float res = lseRow(q, gv);
    if (lane == 0) {
      f_l[wave * 4 + r] = res;
      Fv[b * NN + r0 + r] = res;
    }
  }
  __syncthreads();
  // pass B: columns t and 512+t over this slab's 32 rows (L2-hot re-read)
  float m0 = -1e30f, s0 = 0.f, m1 = -1e30f, s1 = 0.f;
  const _Float16* cp = Pb + (size_t)(slab * 32) * NN;
#pragma unroll 4
  for (int i = 0; i < 32; ++i) {
    float fi = f_l[i];
    float x0 = (float)cp[(size_t)i * NN + t] + fi;
    float x1 = (float)cp[(size_t)i * NN + 512 + t] + fi;
    float mn0 = fmaxf(m0, x0);
    s0 = s0 * EXP2F(m0 - mn0) + EXP2F(x0 - mn0);
    m0 = mn0;
    float mn1 = fmaxf(m1, x1);
    s1 = s1 * EXP2F(m1 - mn1) + EXP2F(x1 - mn1);
    m1 = mn1;
  }
  float* pp = partials + ((size_t)(b * 32 + slab)) * NN * 2;
  st2_cv(pp + 2 * t, m0, s0);
  st2_cv(pp + 2 * (512 + t), m1, s1);
  asm volatile("s_waitcnt vmcnt(0)" ::: "memory");
  __syncthreads();
  if (t == 0) {
    unsigned old = atomicAdd(cnt + b, 1u);
    isLast = (old == 31u);
  }
  __syncthreads();
  if (!isLast) return;
  // combiner tail: this block is the last arriver for batch b
  const float* pbase = partials + ((size_t)(b * 32)) * NN * 2;
#pragma unroll
  for (int half = 0; half < 2; ++half) {
    int j = t + half * 512;
    float M = -1e30f, S = 0.f;
#pragma unroll 8
    for (int s = 0; s < 32; ++s) {
      float2 p = *(const float2*)(pbase + (size_t)s * NN * 2 + 2 * j);
      float Mn = fmaxf(M, p.x);
      S = S * EXP2F(M - Mn) + p.y * EXP2F(p.x - Mn);
      M = Mn;
    }
    gout[b * NN + j] = BASE2 - (M + LOG2F(S));
  }
}

// ---------------- K4: marginals both directions (z) ----------------
__global__ __launch_bounds__(512) void marginals_kernel(
    const _Float16* __restrict__ A2, const _Float16* __restrict__ A2T,
    const float* __restrict__ F, const float* __restrict__ G,
    float* __restrict__ rOut, float* __restrict__ cOut,
    float* __restrict__ Lrow) {
  __shared__ float lv[NN + NN / 8];
  const int z = blockIdx.z;
  const int b = blockIdx.y, sub = blockIdx.x;  // sub 0..7
  const _Float16* P = z ? A2T : A2;
  const float* rowv = z ? G : F;
  const float* colv = z ? F : G;
  float* outS = z ? cOut : rOut;
  const int t = threadIdx.x, lane = t & 63, wave = t >> 6;
  float2 v = *(const float2*)(colv + b * NN + 2 * t);
  lv[PIDX(2 * t + 0)] = v.x;
  lv[PIDX(2 * t + 1)] = v.y;
  __syncthreads();
  const int j0 = lane * 8;
  float gv[16];
  ldsVec16p(lv, j0, gv);
  const _Float16* Pb = P + (size_t)b * NN * NN;
  const int wg = sub * 8 + wave;               // 0..63
  for (int s = 0; s < 16; ++s) {
    int i = wg + s * 64;
    float fi = rowv[b * NN + i];
    const _Float16* row = Pb + (size_t)i * NN;
    h8 qa = *(const h8*)(row + j0);
    h8 qb = *(const h8*)(row + 512 + j0);
    float fr = (float)i;
    float sr = 0.f, sl = 0.f;
#pragma unroll
    for (int k = 0; k < 8; ++k) {
      float a2a = (float)qa[k];
      float a2b = (float)qb[k];
      float Ta = EXP2F(a2a + fi + gv[k]);
      float Tb = EXP2F(a2b + fi + gv[8 + k]);
      sr += Ta + Tb;
      float ca = a2a + CPOS2 * fabsf(fr - (float)(j0 + k));
      float cb = a2b + CPOS2 * fabsf(fr - (float)(512 + j0 + k));
      sl = fmaf(Ta, ca, sl);
      sl = fmaf(Tb, cb, sl);
    }
    sr = waveReduceSum(sr);
    sl = waveReduceSum(sl);
    if (lane == 0) {
      outS[b * NN + i] = sr;
      if (!z) Lrow[b * NN + i] = -C1 * sl;
    }
  }
}

// ---------------- K6: MFMA bary, both directions in one dispatch (z) --------
__global__ __launch_bounds__(256) void bary_mfma_kernel(
    const _Float16* __restrict__ A2, const _Float16* __restrict__ A2T,
    const float* __restrict__ F, const float* __restrict__ G,
    const float* __restrict__ r, const float* __restrict__ c,
    const _Float16* __restrict__ XT, const _Float16* __restrict__ YT,
    const float* __restrict__ X, const float* __restrict__ Y,
    float* __restrict__ baryA, float* __restrict__ baryB) {
  __shared__ float gl[NN];
  __shared__ float red[4];
  const int z = blockIdx.z;
  const _Float16* P = z ? A2T : A2;
  const float* rowv = z ? G : F;
  const float* colv = z ? F : G;
  const float* denom = z ? c : r;
  const _Float16* EmbT = z ? XT : YT;
  const float* Ref = z ? Y : X;
  float* baryAcc = z ? baryB : baryA;
  const int b = blockIdx.y;
  const int I0 = blockIdx.x * 64;
  const int t = threadIdx.x, lane = t & 63, wave = t >> 6;
  const int m = lane & 15, quad = lane >> 4;
  gl[t] = colv[b * NN + t];
  gl[t + 256] = colv[b * NN + t + 256];
  gl[t + 512] = colv[b * NN + t + 512];
  gl[t + 768] = colv[b * NN + t + 768];
  __syncthreads();
  const int row = I0 + wave * 16 + m;
  const float fi = rowv[b * NN + row] + 10.0f;        // fold 2^10 scale
  const _Float16* Pr = P + (size_t)b * NN * NN + (size_t)row * NN + quad * 8;
  const _Float16* ET = EmbT + (size_t)b * DD * NN;
  f32x4 acc[16];
#pragma unroll
  for (int i = 0; i < 16; ++i) acc[i] = (f32x4){0.f, 0.f, 0.f, 0.f};
  for (int kc = 0; kc < NN; kc += 32) {
    h8 a2v = *(const h8*)(Pr + kc);
    float4 g0 = *(const float4*)&gl[kc + quad * 8];
    float4 g1 = *(const float4*)&gl[kc + quad * 8 + 4];
    h8 af;
    af[0] = (_Float16)EXP2F((float)a2v[0] + fi + g0.x);
    af[1] = (_Float16)EXP2F((float)a2v[1] + fi + g0.y);
    af[2] = (_Float16)EXP2F((float)a2v[2] + fi + g0.z);
    af[3] = (_Float16)EXP2F((float)a2v[3] + fi + g0.w);
    af[4] = (_Float16)EXP2F((float)a2v[4] + fi + g1.x);
    af[5] = (_Float16)EXP2F((float)a2v[5] + fi + g1.y);
    af[6] = (_Float16)EXP2F((float)a2v[6] + fi + g1.z);
    af[7] = (_Float16)EXP2F((float)a2v[7] + fi + g1.w);
#pragma unroll
    for (int nt = 0; nt < 16; ++nt) {
      h8 bf = *(const h8*)(ET + (size_t)(nt * 16 + m) * NN + kc + quad * 8);
      acc[nt] = __builtin_amdgcn_mfma_f32_16x16x32_f16(af, bf, acc[nt], 0, 0, 0);
    }
  }
  float vs = 0.f;
#pragma unroll
  for (int r4 = 0; r4 < 4; ++r4) {
    int iabs = I0 + wave * 16 + quad * 4 + r4;
    float inv = 1.0f / (1024.0f * (denom[b * NN + iabs] + 1e-8f));
    const float* Rrow = Ref + ((size_t)b * NN + iabs) * DD;
#pragma unroll
    for (int nt = 0; nt < 16; ++nt) {
      int d = nt * 16 + m;
      float val = Rrow[d] - acc[nt][r4] * inv;
      vs = fmaf(val, val, vs);
    }
  }
  vs = waveReduceSum(vs);
  if (lane == 0) red[wave] = vs;
  __syncthreads();
  if (t == 0) atomicAdd(baryAcc + b, red[0] + red[1] + red[2] + red[3]);
}

// ---------------- K7: partial global sums X*r, Y*c ----------------
__global__ __launch_bounds__(256) void xg_kernel(
    const float* __restrict__ X, const float* __restrict__ Y,
    const float* __restrict__ r, const float* __restrict__ c,
    float* __restrict__ xgp, float* __restrict__ ygp) {
  const int b = blockIdx.y, seg = blockIdx.x, d = threadIdx.x;
  float ax = 0.f, ay = 0.f;
  for (int ii = 0; ii < 256; ++ii) {
    int i = seg * 256 + ii;
    float rvv = r[b * NN + i];
    float cvv = c[b * NN + i];
    ax = fmaf(X[((size_t)b * NN + i) * DD + d], rvv, ax);
    ay = fmaf(Y[((size_t)b * NN + i) * DD + d], cvv, ay);
  }
  xgp[(size_t)(b * 4 + seg) * DD + d] = ax;
  ygp[(size_t)(b * 4 + seg) * DD + d] = ay;
}

// ---------------- K8: per-batch finalize ----------------
__global__ __launch_bounds__(256) void finalize_batch(
    const float* __restrict__ r, const float* __restrict__ c,
    const float* __restrict__ Lrow, const float* __restrict__ xgp,
    const float* __restrict__ ygp, const float* __restrict__ baryA,
    const float* __restrict__ baryB, float* __restrict__ lossArr) {
  const int b = blockIdx.x;
  const int t = threadIdx.x;
  __shared__ float sd[256];
  auto bsum = [&](float v) -> float {
    sd[t] = v; __syncthreads();
    for (int o = 128; o; o >>= 1) { if (t < o) sd[t] += sd[t + o]; __syncthreads(); }
    float res = sd[0]; __syncthreads();
    return res;
  };
  float vr = 0.f, vc = 0.f, vl = 0.f;
  for (int k = 0; k < 4; ++k) {
    int i = t + 256 * k;
    vr += r[b * NN + i];
    vc += c[b * NN + i];
    vl += Lrow[b * NN + i];
  }
  float sumR = bsum(vr);
  float sumC = bsum(vc);
  float Lmain = bsum(vl);
  float xg = (xgp[(size_t)(b * 4 + 0) * DD + t] + xgp[(size_t)(b * 4 + 1) * DD + t] +
              xgp[(size_t)(b * 4 + 2) * DD + t] + xgp[(size_t)(b * 4 + 3) * DD + t]) /
             (sumR + 1e-8f);
  float yg = (ygp[(size_t)(b * 4 + 0) * DD + t] + ygp[(size_t)(b * 4 + 1) * DD + t] +
              ygp[(size_t)(b * 4 + 2) * DD + t] + ygp[(size_t)(b * 4 + 3) * DD + t]) /
             (sumC + 1e-8f);
  float nx = bsum(xg * xg);
  float ny = bsum(yg * yg);
  float dt = bsum(xg * yg);
  if (t == 0) {
    float mx = fmaxf(sqrtf(nx), 1e-12f);
    float my = fmaxf(sqrtf(ny), 1e-12f);
    float cosv = dt / (mx * my);
    float lb = (baryA[b] + baryB[b]) * (1.0f / ((float)NN * (float)DD));
    lossArr[b] = Lmain + 0.5f * lb + 0.2f * (1.0f - cosv);
  }
}

__global__ void final_mean(const float* __restrict__ lossArr, float* __restrict__ out) {
  int t = threadIdx.x;
  float v = (t < BB) ? lossArr[t] : 0.f;
  v = waveReduceSum(v);
  if (t == 0) out[0] = v * (1.0f / BB);
}

// ---------------- launch ----------------
extern "C" void kernel_launch(void* const* d_in, const int* in_sizes, int n_in,
                              void* d_out, int out_size, void* d_ws, size_t ws_size,
                              hipStream_t stream) {
  const float* X = (const float*)d_in[0];
  const float* Y = (const float*)d_in[1];
  float* out = (float*)d_out;
  char* ws = (char*)d_ws;
  size_t off = 0;
  auto take = [&](size_t bytes) -> char* {
    char* p = ws + off;
    off = (off + bytes + 255) & ~(size_t)255;
    return p;
  };
  _Float16* Xh = (_Float16*)take((size_t)BB * NN * DD * 2);
  _Float16* Yh = (_Float16*)take((size_t)BB * NN * DD * 2);
  _Float16* XT_h = (_Float16*)take((size_t)BB * DD * NN * 2);
  _Float16* YT_h = (_Float16*)take((size_t)BB * DD * NN * 2);
  _Float16* A2 = (_Float16*)take((size_t)BB * NN * NN * 2);
  _Float16* A2T = (_Float16*)take((size_t)BB * NN * NN * 2);
  float* part = (float*)take((size_t)BB * 32 * NN * 2 * 4);   // (m,s) partials, 4 MB
  size_t zstart = off;
  float* G0 = (float*)take((size_t)BB * NN * 4);
  unsigned* cnt = (unsigned*)take(50 * BB * 4);
  float* baryA = (float*)take(64);
  float* baryB = (float*)take(64);
  size_t zlen = off - zstart;
  float* G1 = (float*)take((size_t)BB * NN * 4);
  float* Fv = (float*)take((size_t)BB * NN * 4);
  float* r = (float*)take((size_t)BB * NN * 4);
  float* c = (float*)take((size_t)BB * NN * 4);
  float* Lrow = (float*)take((size_t)BB * NN * 4);
  float* xgp = (float*)take((size_t)BB * 4 * DD * 4);
  float* ygp = (float*)take((size_t)BB * 4 * DD * 4);
  float* lossArr = (float*)take(64);
  (void)in_sizes; (void)n_in; (void)out_size; (void)ws_size;

  hipMemsetAsync(ws + zstart, 0, zlen, stream);

  normalize_kernel<<<dim3(2 * BB * NN / 4), dim3(256), 0, stream>>>(X, Y, Xh, Yh);
  transpose_kernel<<<dim3(NN / 64, DD / 64, 2 * BB), dim3(256), 0, stream>>>(X, Y, XT_h,
                                                                             YT_h);
  gemm_a2_kernel<<<dim3(NN / 128, NN / 128, 2 * BB), dim3(256), 0, stream>>>(Xh, Yh, A2,
                                                                             A2T);
  float* gbuf[2] = {G0, G1};
  for (int it = 0; it < 50; ++it) {
    sink_iter_kernel<<<dim3(32, BB), dim3(512), 0, stream>>>(
        A2, gbuf[it & 1], gbuf[(it + 1) & 1], Fv, part, cnt + it * BB);
  }
  float* Gf = gbuf[0];   // final g after 50 iterations (even count)
  marginals_kernel<<<dim3(8, BB, 2), dim3(512), 0, stream>>>(A2, A2T, Fv, Gf, r, c,
                                                             Lrow);
  bary_mfma_kernel<<<dim3(NN / 64, BB, 2), dim3(256), 0, stream>>>(
      A2, A2T, Fv, Gf, r, c, XT_h, YT_h, X, Y, baryA, baryB);
  xg_kernel<<<dim3(4, BB), dim3(256), 0, stream>>>(X, Y, r, c, xgp, ygp);
  finalize_batch<<<dim3(BB), dim3(256), 0, stream>>>(r, c, Lrow, xgp, ygp, baryA, baryB,
                                                     lossArr);
  final_mean<<<dim3(1), dim3(64), 0, stream>>>(lossArr, out);
}

// Round 11
// 1296.042 us; speedup vs baseline: 1.0630x; 1.0630x over previous
//
#include <hip/hip_runtime.h>
#include <hip/hip_fp16.h>

#define BB 16
#define NN 1024
#define DD 256

typedef _Float16 h8 __attribute__((ext_vector_type(8)));
typedef _Float16 hv4 __attribute__((ext_vector_type(4)));
typedef float f32x4 __attribute__((ext_vector_type(4)));

#if __has_builtin(__builtin_amdgcn_exp2f)
#define EXP2F(x) __builtin_amdgcn_exp2f(x)
#else
#define EXP2F(x) exp2f(x)
#endif
#if __has_builtin(__builtin_amdgcn_logf)
#define LOG2F(x) __builtin_amdgcn_logf(x)
#else
#define LOG2F(x) log2f(x)
#endif

// log2-domain: A2s = -100*log2e*relu(1-S) - CPOS2*|i-j|   (pos prior folded in, fp16)
constexpr float K_A2  = -144.26950408889634f;                 // -100*log2(e)
constexpr float CPOS2 = (float)(0.2 * 1.4426950408889634 / 1023.0);
constexpr float C1    = 0.06931471805599453f;                 // ln2/10
constexpr float BASE2 = -10.0f;                               // log2(1/1024 + 1e-12)

#define PIDX(i) ((i) + ((i) >> 3))

__device__ __forceinline__ float waveReduceSum(float v) {
#pragma unroll
  for (int o = 32; o; o >>= 1) v += __shfl_xor(v, o);
  return v;
}

__device__ __forceinline__ void ldsVec16p(const float* lds, int j0, float (&out)[16]) {
#pragma unroll
  for (int k = 0; k < 8; ++k) {
    out[k] = lds[PIDX(j0 + k)];
    out[8 + k] = lds[PIDX(512 + j0 + k)];
  }
}

__device__ __forceinline__ float lseRow(const h8 (&rw)[2], const float (&gv)[16]) {
  float x[16];
#pragma unroll
  for (int k = 0; k < 8; ++k) {
    x[k]     = (float)rw[0][k] + gv[k];
    x[8 + k] = (float)rw[1][k] + gv[8 + k];
  }
  float m = x[0];
#pragma unroll
  for (int k = 1; k < 16; ++k) m = fmaxf(m, x[k]);
#pragma unroll
  for (int o = 32; o; o >>= 1) m = fmaxf(m, __shfl_xor(m, o));
  float s = 0.f;
#pragma unroll
  for (int k = 0; k < 16; ++k) s += EXP2F(x[k] - m);
  s = waveReduceSum(s);
  return BASE2 - (m + LOG2F(s));
}

// ---------------- K1: normalize rows of X and Y -> fp16 ----------------
__global__ __launch_bounds__(256) void normalize_kernel(
    const float* __restrict__ X, const float* __restrict__ Y,
    _Float16* __restrict__ Xh, _Float16* __restrict__ Yh) {
  int wave = threadIdx.x >> 6;
  int lane = threadIdx.x & 63;
  int row = blockIdx.x * 4 + wave;
  const float* src;
  _Float16* dst;
  if (row < BB * NN) { src = X + (size_t)row * DD; dst = Xh + (size_t)row * DD; }
  else { int r2 = row - BB * NN; src = Y + (size_t)r2 * DD; dst = Yh + (size_t)r2 * DD; }
  float4 v = *(const float4*)(src + lane * 4);
  float ss = v.x * v.x + v.y * v.y + v.z * v.z + v.w * v.w;
  ss = waveReduceSum(ss);
  float sc = 1.0f / fmaxf(sqrtf(ss), 1e-12f);
  hv4 hv;
  hv[0] = (_Float16)(v.x * sc); hv[1] = (_Float16)(v.y * sc);
  hv[2] = (_Float16)(v.z * sc); hv[3] = (_Float16)(v.w * sc);
  *(hv4*)(dst + lane * 4) = hv;
}

// ---------------- K1b: tiled transpose X,Y -> fp16 [b][d][n] ----------------
__global__ __launch_bounds__(256) void transpose_kernel(
    const float* __restrict__ X, const float* __restrict__ Y,
    _Float16* __restrict__ XT, _Float16* __restrict__ YT) {
  __shared__ _Float16 tile[64][72];
  int zb = blockIdx.z;
  const float* E;
  _Float16* ET;
  if (zb < BB) { E = X + (size_t)zb * NN * DD; ET = XT + (size_t)zb * DD * NN; }
  else { E = Y + (size_t)(zb - BB) * NN * DD; ET = YT + (size_t)(zb - BB) * DD * NN; }
  int n0 = blockIdx.x * 64, d0 = blockIdx.y * 64;
  int t = threadIdx.x;
  int lr = t >> 2, lc = (t & 3) * 16;
#pragma unroll
  for (int k = 0; k < 16; k += 4) {
    float4 v = *(const float4*)(E + (size_t)(n0 + lr) * DD + d0 + lc + k);
    tile[lc + k + 0][lr] = (_Float16)v.x;
    tile[lc + k + 1][lr] = (_Float16)v.y;
    tile[lc + k + 2][lr] = (_Float16)v.z;
    tile[lc + k + 3][lr] = (_Float16)v.w;
  }
  __syncthreads();
#pragma unroll
  for (int k = 0; k < 16; k += 8) {
    h8 o;
#pragma unroll
    for (int j = 0; j < 8; ++j) o[j] = tile[lr][lc + k + j];
    *(h8*)(ET + (size_t)(d0 + lr) * NN + n0 + lc + k) = o;
  }
}

// ---------------- K2: both S-gemms in one dispatch (z = dir*16 + b) ----------
__global__ __launch_bounds__(256) void gemm_a2_kernel(
    const _Float16* __restrict__ Xh, const _Float16* __restrict__ Yh,
    _Float16* __restrict__ A2, _Float16* __restrict__ A2T) {
  const int zb = blockIdx.z;
  const int b = zb & 15;
  const _Float16* Ah = (zb < BB) ? Xh : Yh;
  const _Float16* Bh = (zb < BB) ? Yh : Xh;
  _Float16* Out = (zb < BB) ? A2 : A2T;
  const int I0 = blockIdx.y * 128;
  const int J0 = blockIdx.x * 128;
  const int lane = threadIdx.x & 63;
  const int wave = threadIdx.x >> 6;
  const int m = lane & 15, quad = lane >> 4;
  const _Float16* Abase = Ah + ((size_t)b * NN + I0 + wave * 32) * DD;
  const _Float16* Bbase = Bh + ((size_t)b * NN + J0) * DD;
  f32x4 acc[2][8] = {};
  for (int k0 = 0; k0 < DD; k0 += 32) {
    int koff = k0 + quad * 8;
    h8 a0 = *(const h8*)(Abase + (size_t)m * DD + koff);
    h8 a1 = *(const h8*)(Abase + (size_t)(m + 16) * DD + koff);
#pragma unroll
    for (int t = 0; t < 8; ++t) {
      h8 bf = *(const h8*)(Bbase + (size_t)(t * 16 + m) * DD + koff);
      acc[0][t] = __builtin_amdgcn_mfma_f32_16x16x32_f16(a0, bf, acc[0][t], 0, 0, 0);
      acc[1][t] = __builtin_amdgcn_mfma_f32_16x16x32_f16(a1, bf, acc[1][t], 0, 0, 0);
    }
  }
  _Float16* Ob = Out + ((size_t)b * NN + I0 + wave * 32) * NN + J0;
#pragma unroll
  for (int a = 0; a < 2; ++a)
#pragma unroll
    for (int t = 0; t < 8; ++t)
#pragma unroll
      for (int r = 0; r < 4; ++r) {
        int row = a * 16 + quad * 4 + r;
        int col = t * 16 + m;
        float s = acc[a][t][r];
        float ri = (float)(I0 + wave * 32 + row);
        float ci = (float)(J0 + col);
        Ob[(size_t)row * NN + col] =
            (_Float16)(K_A2 * fmaxf(1.0f - s, 0.0f) - CPOS2 * fabsf(ri - ci));
      }
}

// ---------------- K3: one full sinkhorn iteration, NO cross-block waits --------
// Partials (m,s per column per slab, fp16) flow between dispatches as PLAIN
// cached stores/loads (dispatch-boundary release/acquire handles coherence).
// Every block redundantly combines its batch's 32 slab-partials into g at the
// start (L2-shared 128 KB read, ~300 cycles of merges) - no serial combiner
// tail (round 10's 21.6 us/iter failure mode), no atomics, no uncached ops.
// grid (32 slabs, BB) x 512 thr; block owns 32 rows of A2.
__global__ __launch_bounds__(512) void sink_iter_kernel(
    const _Float16* __restrict__ A2, const _Float16* __restrict__ partIn,
    _Float16* __restrict__ partOut, float* __restrict__ Fv, int first) {
  __shared__ float lv[NN + NN / 8];
  __shared__ float f_l[32];
  const int b = blockIdx.y;
  const int slab = blockIdx.x;                  // 0..31
  const int t = threadIdx.x, lane = t & 63, wave = t >> 6;   // 8 waves
  // prologue: combine partials -> g (cols 2t, 2t+1), or g=0 on first iteration
  if (first) {
    lv[PIDX(2 * t)] = 0.f;
    lv[PIDX(2 * t + 1)] = 0.f;
  } else {
    float M0 = -1e30f, S0 = 0.f, M1 = -1e30f, S1 = 0.f;
    const _Float16* pb = partIn + ((size_t)(b * 32) * NN + 2 * t) * 2;
#pragma unroll 8
    for (int s = 0; s < 32; ++s) {
      hv4 p = *(const hv4*)(pb + (size_t)s * NN * 2);
      float m0 = (float)p[0], v0 = (float)p[1];
      float m1 = (float)p[2], v1 = (float)p[3];
      float Mn0 = fmaxf(M0, m0);
      S0 = S0 * EXP2F(M0 - Mn0) + v0 * EXP2F(m0 - Mn0);
      M0 = Mn0;
      float Mn1 = fmaxf(M1, m1);
      S1 = S1 * EXP2F(M1 - Mn1) + v1 * EXP2F(m1 - Mn1);
      M1 = Mn1;
    }
    lv[PIDX(2 * t)] = BASE2 - (M0 + LOG2F(S0));
    lv[PIDX(2 * t + 1)] = BASE2 - (M1 + LOG2F(S1));
  }
  __syncthreads();
  const int j0 = lane * 8;
  float gv[16];
  ldsVec16p(lv, j0, gv);
  const _Float16* Pb = A2 + (size_t)b * NN * NN;
  const int r0 = slab * 32 + wave * 4;
  // pass A: 4 rows per wave -> f
#pragma unroll
  for (int r = 0; r < 4; ++r) {
    h8 q[2];
    q[0] = *(const h8*)(Pb + (size_t)(r0 + r) * NN + j0);
    q[1] = *(const h8*)(Pb + (size_t)(r0 + r) * NN + 512 + j0);
    float res = lseRow(q, gv);
    if (lane == 0) {
      f_l[wave * 4 + r] = res;
      Fv[b * NN + r0 + r] = res;
    }
  }
  __syncthreads();
  // pass B: partial column-lse over this slab's 32 rows (L2-hot re-read)
  float m0 = -1e30f, s0 = 0.f, m1 = -1e30f, s1 = 0.f;
  const _Float16* cp = Pb + (size_t)(slab * 32) * NN + 2 * t;
#pragma unroll 8
  for (int i = 0; i < 32; ++i) {
    float fi = f_l[i];
    hv4 dummy;
    float2h: ;
    _Float16 a0 = cp[(size_t)i * NN];
    _Float16 a1 = cp[(size_t)i * NN + 1];
    float x0 = (float)a0 + fi;
    float x1 = (float)a1 + fi;
    float mn0 = fmaxf(m0, x0);
    s0 = s0 * EXP2F(m0 - mn0) + EXP2F(x0 - mn0);
    m0 = mn0;
    float mn1 = fmaxf(m1, x1);
    s1 = s1 * EXP2F(m1 - mn1) + EXP2F(x1 - mn1);
    m1 = mn1;
  }
  hv4 o;
  o[0] = (_Float16)m0; o[1] = (_Float16)s0;
  o[2] = (_Float16)m1; o[3] = (_Float16)s1;
  *(hv4*)(partOut + ((size_t)(b * 32 + slab) * NN + 2 * t) * 2) = o;
}

// ---------------- K3b: final g = combine(partials) ----------------
__global__ __launch_bounds__(512) void combine_g_kernel(
    const _Float16* __restrict__ partIn, float* __restrict__ Gf) {
  const int b = blockIdx.x;
  const int t = threadIdx.x;
  float M0 = -1e30f, S0 = 0.f, M1 = -1e30f, S1 = 0.f;
  const _Float16* pb = partIn + ((size_t)(b * 32) * NN + 2 * t) * 2;
#pragma unroll 8
  for (int s = 0; s < 32; ++s) {
    hv4 p = *(const hv4*)(pb + (size_t)s * NN * 2);
    float m0 = (float)p[0], v0 = (float)p[1];
    float m1 = (float)p[2], v1 = (float)p[3];
    float Mn0 = fmaxf(M0, m0);
    S0 = S0 * EXP2F(M0 - Mn0) + v0 * EXP2F(m0 - Mn0);
    M0 = Mn0;
    float Mn1 = fmaxf(M1, m1);
    S1 = S1 * EXP2F(M1 - Mn1) + v1 * EXP2F(m1 - Mn1);
    M1 = Mn1;
  }
  Gf[b * NN + 2 * t] = BASE2 - (M0 + LOG2F(S0));
  Gf[b * NN + 2 * t + 1] = BASE2 - (M1 + LOG2F(S1));
}

// ---------------- K4: marginals both directions (z) ----------------
__global__ __launch_bounds__(512) void marginals_kernel(
    const _Float16* __restrict__ A2, const _Float16* __restrict__ A2T,
    const float* __restrict__ F, const float* __restrict__ G,
    float* __restrict__ rOut, float* __restrict__ cOut,
    float* __restrict__ Lrow) {
  __shared__ float lv[NN + NN / 8];
  const int z = blockIdx.z;
  const int b = blockIdx.y, sub = blockIdx.x;  // sub 0..7
  const _Float16* P = z ? A2T : A2;
  const float* rowv = z ? G : F;
  const float* colv = z ? F : G;
  float* outS = z ? cOut : rOut;
  const int t = threadIdx.x, lane = t & 63, wave = t >> 6;
  float2 v = *(const float2*)(colv + b * NN + 2 * t);
  lv[PIDX(2 * t + 0)] = v.x;
  lv[PIDX(2 * t + 1)] = v.y;
  __syncthreads();
  const int j0 = lane * 8;
  float gv[16];
  ldsVec16p(lv, j0, gv);
  const _Float16* Pb = P + (size_t)b * NN * NN;
  const int wg = sub * 8 + wave;               // 0..63
  for (int s = 0; s < 16; ++s) {
    int i = wg + s * 64;
    float fi = rowv[b * NN + i];
    const _Float16* row = Pb + (size_t)i * NN;
    h8 qa = *(const h8*)(row + j0);
    h8 qb = *(const h8*)(row + 512 + j0);
    float fr = (float)i;
    float sr = 0.f, sl = 0.f;
#pragma unroll
    for (int k = 0; k < 8; ++k) {
      float a2a = (float)qa[k];
      float a2b = (float)qb[k];
      float Ta = EXP2F(a2a + fi + gv[k]);
      float Tb = EXP2F(a2b + fi + gv[8 + k]);
      sr += Ta + Tb;
      float ca = a2a + CPOS2 * fabsf(fr - (float)(j0 + k));
      float cb = a2b + CPOS2 * fabsf(fr - (float)(512 + j0 + k));
      sl = fmaf(Ta, ca, sl);
      sl = fmaf(Tb, cb, sl);
    }
    sr = waveReduceSum(sr);
    sl = waveReduceSum(sl);
    if (lane == 0) {
      outS[b * NN + i] = sr;
      if (!z) Lrow[b * NN + i] = -C1 * sl;
    }
  }
}

// ---------------- K6: MFMA bary, dir x d-half split (z = dir + 2*dhalf) --------
__global__ __launch_bounds__(256) void bary_mfma_kernel(
    const _Float16* __restrict__ A2, const _Float16* __restrict__ A2T,
    const float* __restrict__ F, const float* __restrict__ G,
    const float* __restrict__ r, const float* __restrict__ c,
    const _Float16* __restrict__ XT, const _Float16* __restrict__ YT,
    const float* __restrict__ X, const float* __restrict__ Y,
    float* __restrict__ baryA, float* __restrict__ baryB) {
  __shared__ float gl[NN];
  __shared__ float red[4];
  const int z = blockIdx.z;
  const int dir = z & 1, dhalf = z >> 1;
  const _Float16* P = dir ? A2T : A2;
  const float* rowv = dir ? G : F;
  const float* colv = dir ? F : G;
  const float* denom = dir ? c : r;
  const _Float16* EmbT = dir ? XT : YT;
  const float* Ref = dir ? Y : X;
  float* baryAcc = dir ? baryB : baryA;
  const int b = blockIdx.y;
  const int I0 = blockIdx.x * 64;
  const int t = threadIdx.x, lane = t & 63, wave = t >> 6;
  const int m = lane & 15, quad = lane >> 4;
  gl[t] = colv[b * NN + t];
  gl[t + 256] = colv[b * NN + t + 256];
  gl[t + 512] = colv[b * NN + t + 512];
  gl[t + 768] = colv[b * NN + t + 768];
  __syncthreads();
  const int row = I0 + wave * 16 + m;
  const float fi = rowv[b * NN + row] + 10.0f;        // fold 2^10 scale
  const _Float16* Pr = P + (size_t)b * NN * NN + (size_t)row * NN + quad * 8;
  const _Float16* ET = EmbT + (size_t)b * DD * NN + (size_t)(dhalf * 128) * NN;
  f32x4 acc[8];
#pragma unroll
  for (int i = 0; i < 8; ++i) acc[i] = (f32x4){0.f, 0.f, 0.f, 0.f};
  for (int kc = 0; kc < NN; kc += 32) {
    h8 a2v = *(const h8*)(Pr + kc);
    float4 g0 = *(const float4*)&gl[kc + quad * 8];
    float4 g1 = *(const float4*)&gl[kc + quad * 8 + 4];
    h8 af;
    af[0] = (_Float16)EXP2F((float)a2v[0] + fi + g0.x);
    af[1] = (_Float16)EXP2F((float)a2v[1] + fi + g0.y);
    af[2] = (_Float16)EXP2F((float)a2v[2] + fi + g0.z);
    af[3] = (_Float16)EXP2F((float)a2v[3] + fi + g0.w);
    af[4] = (_Float16)EXP2F((float)a2v[4] + fi + g1.x);
    af[5] = (_Float16)EXP2F((float)a2v[5] + fi + g1.y);
    af[6] = (_Float16)EXP2F((float)a2v[6] + fi + g1.z);
    af[7] = (_Float16)EXP2F((float)a2v[7] + fi + g1.w);
#pragma unroll
    for (int nt = 0; nt < 8; ++nt) {
      h8 bf = *(const h8*)(ET + (size_t)(nt * 16 + m) * NN + kc + quad * 8);
      acc[nt] = __builtin_amdgcn_mfma_f32_16x16x32_f16(af, bf, acc[nt], 0, 0, 0);
    }
  }
  float vs = 0.f;
#pragma unroll
  for (int r4 = 0; r4 < 4; ++r4) {
    int iabs = I0 + wave * 16 + quad * 4 + r4;
    float inv = 1.0f / (1024.0f * (denom[b * NN + iabs] + 1e-8f));
    const float* Rrow = Ref + ((size_t)b * NN + iabs) * DD + dhalf * 128;
#pragma unroll
    for (int nt = 0; nt < 8; ++nt) {
      int d = nt * 16 + m;
      float val = Rrow[d] - acc[nt][r4] * inv;
      vs = fmaf(val, val, vs);
    }
  }
  vs = waveReduceSum(vs);
  if (lane == 0) red[wave] = vs;
  __syncthreads();
  if (t == 0) atomicAdd(baryAcc + b, red[0] + red[1] + red[2] + red[3]);
}

// ---------------- K7: partial global sums X*r, Y*c ----------------
__global__ __launch_bounds__(256) void xg_kernel(
    const float* __restrict__ X, const float* __restrict__ Y,
    const float* __restrict__ r, const float* __restrict__ c,
    float* __restrict__ xgp, float* __restrict__ ygp) {
  const int b = blockIdx.y, seg = blockIdx.x, d = threadIdx.x;
  float ax = 0.f, ay = 0.f;
  for (int ii = 0; ii < 256; ++ii) {
    int i = seg * 256 + ii;
    float rvv = r[b * NN + i];
    float cvv = c[b * NN + i];
    ax = fmaf(X[((size_t)b * NN + i) * DD + d], rvv, ax);
    ay = fmaf(Y[((size_t)b * NN + i) * DD + d], cvv, ay);
  }
  xgp[(size_t)(b * 4 + seg) * DD + d] = ax;
  ygp[(size_t)(b * 4 + seg) * DD + d] = ay;
}

// ---------------- K8: per-batch finalize ----------------
__global__ __launch_bounds__(256) void finalize_batch(
    const float* __restrict__ r, const float* __restrict__ c,
    const float* __restrict__ Lrow, const float* __restrict__ xgp,
    const float* __restrict__ ygp, const float* __restrict__ baryA,
    const float* __restrict__ baryB, float* __restrict__ lossArr) {
  const int b = blockIdx.x;
  const int t = threadIdx.x;
  __shared__ float sd[256];
  auto bsum = [&](float v) -> float {
    sd[t] = v; __syncthreads();
    for (int o = 128; o; o >>= 1) { if (t < o) sd[t] += sd[t + o]; __syncthreads(); }
    float res = sd[0]; __syncthreads();
    return res;
  };
  float vr = 0.f, vc = 0.f, vl = 0.f;
  for (int k = 0; k < 4; ++k) {
    int i = t + 256 * k;
    vr += r[b * NN + i];
    vc += c[b * NN + i];
    vl += Lrow[b * NN + i];
  }
  float sumR = bsum(vr);
  float sumC = bsum(vc);
  float Lmain = bsum(vl);
  float xg = (xgp[(size_t)(b * 4 + 0) * DD + t] + xgp[(size_t)(b * 4 + 1) * DD + t] +
              xgp[(size_t)(b * 4 + 2) * DD + t] + xgp[(size_t)(b * 4 + 3) * DD + t]) /
             (sumR + 1e-8f);
  float yg = (ygp[(size_t)(b * 4 + 0) * DD + t] + ygp[(size_t)(b * 4 + 1) * DD + t] +
              ygp[(size_t)(b * 4 + 2) * DD + t] + ygp[(size_t)(b * 4 + 3) * DD + t]) /
             (sumC + 1e-8f);
  float nx = bsum(xg * xg);
  float ny = bsum(yg * yg);
  float dt = bsum(xg * yg);
  if (t == 0) {
    float mx = fmaxf(sqrtf(nx), 1e-12f);
    float my = fmaxf(sqrtf(ny), 1e-12f);
    float cosv = dt / (mx * my);
    float lb = (baryA[b] + baryB[b]) * (1.0f / ((float)NN * (float)DD));
    lossArr[b] = Lmain + 0.5f * lb + 0.2f * (1.0f - cosv);
  }
}

__global__ void final_mean(const float* __restrict__ lossArr, float* __restrict__ out) {
  int t = threadIdx.x;
  float v = (t < BB) ? lossArr[t] : 0.f;
  v = waveReduceSum(v);
  if (t == 0) out[0] = v * (1.0f / BB);
}

// ---------------- launch ----------------
extern "C" void kernel_launch(void* const* d_in, const int* in_sizes, int n_in,
                              void* d_out, int out_size, void* d_ws, size_t ws_size,
                              hipStream_t stream) {
  const float* X = (const float*)d_in[0];
  const float* Y = (const float*)d_in[1];
  float* out = (float*)d_out;
  char* ws = (char*)d_ws;
  size_t off = 0;
  auto take = [&](size_t bytes) -> char* {
    char* p = ws + off;
    off = (off + bytes + 255) & ~(size_t)255;
    return p;
  };
  _Float16* Xh = (_Float16*)take((size_t)BB * NN * DD * 2);
  _Float16* Yh = (_Float16*)take((size_t)BB * NN * DD * 2);
  _Float16* XT_h = (_Float16*)take((size_t)BB * DD * NN * 2);
  _Float16* YT_h = (_Float16*)take((size_t)BB * DD * NN * 2);
  _Float16* A2 = (_Float16*)take((size_t)BB * NN * NN * 2);
  _Float16* A2T = (_Float16*)take((size_t)BB * NN * NN * 2);
  _Float16* P0 = (_Float16*)take((size_t)BB * 32 * NN * 2 * 2);  // (m,s) fp16, 2 MB
  _Float16* P1 = (_Float16*)take((size_t)BB * 32 * NN * 2 * 2);
  size_t zstart = off;
  float* baryA = (float*)take(64);
  float* baryB = (float*)take(64);
  size_t zlen = off - zstart;
  float* Fv = (float*)take((size_t)BB * NN * 4);
  float* Gf = (float*)take((size_t)BB * NN * 4);
  float* r = (float*)take((size_t)BB * NN * 4);
  float* c = (float*)take((size_t)BB * NN * 4);
  float* Lrow = (float*)take((size_t)BB * NN * 4);
  float* xgp = (float*)take((size_t)BB * 4 * DD * 4);
  float* ygp = (float*)take((size_t)BB * 4 * DD * 4);
  float* lossArr = (float*)take(64);
  (void)in_sizes; (void)n_in; (void)out_size; (void)ws_size;

  hipMemsetAsync(ws + zstart, 0, zlen, stream);

  normalize_kernel<<<dim3(2 * BB * NN / 4), dim3(256), 0, stream>>>(X, Y, Xh, Yh);
  transpose_kernel<<<dim3(NN / 64, DD / 64, 2 * BB), dim3(256), 0, stream>>>(X, Y, XT_h,
                                                                             YT_h);
  gemm_a2_kernel<<<dim3(NN / 128, NN / 128, 2 * BB), dim3(256), 0, stream>>>(Xh, Yh, A2,
                                                                             A2T);
  _Float16* pbuf[2] = {P0, P1};
  for (int it = 0; it < 50; ++it) {
    sink_iter_kernel<<<dim3(32, BB), dim3(512), 0, stream>>>(
        A2, pbuf[(it + 1) & 1], pbuf[it & 1], Fv, it == 0 ? 1 : 0);
  }
  combine_g_kernel<<<dim3(BB), dim3(512), 0, stream>>>(pbuf[1], Gf);  // 49&1 == 1
  marginals_kernel<<<dim3(8, BB, 2), dim3(512), 0, stream>>>(A2, A2T, Fv, Gf, r, c,
                                                             Lrow);
  bary_mfma_kernel<<<dim3(NN / 64, BB, 4), dim3(256), 0, stream>>>(
      A2, A2T, Fv, Gf, r, c, XT_h, YT_h, X, Y, baryA, baryB);
  xg_kernel<<<dim3(4, BB), dim3(256), 0, stream>>>(X, Y, r, c, xgp, ygp);
  finalize_batch<<<dim3(BB), dim3(256), 0, stream>>>(r, c, Lrow, xgp, ygp, baryA, baryB,
                                                     lossArr);
  final_mean<<<dim3(1), dim3(64), 0, stream>>>(lossArr, out);
}

// Round 12
// 1214.203 us; speedup vs baseline: 1.1346x; 1.0674x over previous
//
#include <hip/hip_runtime.h>
#include <hip/hip_fp16.h>

#define BB 16
#define NN 1024
#define DD 256

typedef _Float16 h8 __attribute__((ext_vector_type(8)));
typedef _Float16 hv4 __attribute__((ext_vector_type(4)));
typedef _Float16 h2 __attribute__((ext_vector_type(2)));
typedef float f32x4 __attribute__((ext_vector_type(4)));

#if __has_builtin(__builtin_amdgcn_exp2f)
#define EXP2F(x) __builtin_amdgcn_exp2f(x)
#else
#define EXP2F(x) exp2f(x)
#endif
#if __has_builtin(__builtin_amdgcn_logf)
#define LOG2F(x) __builtin_amdgcn_logf(x)
#else
#define LOG2F(x) log2f(x)
#endif

// log2-domain: A2s = -100*log2e*relu(1-S) - CPOS2*|i-j|   (pos prior folded in, fp16)
constexpr float K_A2  = -144.26950408889634f;                 // -100*log2(e)
constexpr float CPOS2 = (float)(0.2 * 1.4426950408889634 / 1023.0);
constexpr float C1    = 0.06931471805599453f;                 // ln2/10
constexpr float BASE2 = -10.0f;                               // log2(1/1024 + 1e-12)

#define PIDX(i) ((i) + ((i) >> 3))

__device__ __forceinline__ float waveReduceSum(float v) {
#pragma unroll
  for (int o = 32; o; o >>= 1) v += __shfl_xor(v, o);
  return v;
}

__device__ __forceinline__ void ldsVec16p(const float* lds, int j0, float (&out)[16]) {
#pragma unroll
  for (int k = 0; k < 8; ++k) {
    out[k] = lds[PIDX(j0 + k)];
    out[8 + k] = lds[PIDX(512 + j0 + k)];
  }
}

__device__ __forceinline__ float lseRow(const h8 (&rw)[2], const float (&gv)[16]) {
  float x[16];
#pragma unroll
  for (int k = 0; k < 8; ++k) {
    x[k]     = (float)rw[0][k] + gv[k];
    x[8 + k] = (float)rw[1][k] + gv[8 + k];
  }
  float m = x[0];
#pragma unroll
  for (int k = 1; k < 16; ++k) m = fmaxf(m, x[k]);
#pragma unroll
  for (int o = 32; o; o >>= 1) m = fmaxf(m, __shfl_xor(m, o));
  float s = 0.f;
#pragma unroll
  for (int k = 0; k < 16; ++k) s += EXP2F(x[k] - m);
  s = waveReduceSum(s);
  return BASE2 - (m + LOG2F(s));
}

// ---------------- K1: normalize rows of X and Y -> fp16 ----------------
__global__ __launch_bounds__(256) void normalize_kernel(
    const float* __restrict__ X, const float* __restrict__ Y,
    _Float16* __restrict__ Xh, _Float16* __restrict__ Yh) {
  int wave = threadIdx.x >> 6;
  int lane = threadIdx.x & 63;
  int row = blockIdx.x * 4 + wave;
  const float* src;
  _Float16* dst;
  if (row < BB * NN) { src = X + (size_t)row * DD; dst = Xh + (size_t)row * DD; }
  else { int r2 = row - BB * NN; src = Y + (size_t)r2 * DD; dst = Yh + (size_t)r2 * DD; }
  float4 v = *(const float4*)(src + lane * 4);
  float ss = v.x * v.x + v.y * v.y + v.z * v.z + v.w * v.w;
  ss = waveReduceSum(ss);
  float sc = 1.0f / fmaxf(sqrtf(ss), 1e-12f);
  hv4 hv;
  hv[0] = (_Float16)(v.x * sc); hv[1] = (_Float16)(v.y * sc);
  hv[2] = (_Float16)(v.z * sc); hv[3] = (_Float16)(v.w * sc);
  *(hv4*)(dst + lane * 4) = hv;
}

// ---------------- K1b: tiled transpose X,Y -> fp16 [b][d][n] ----------------
__global__ __launch_bounds__(256) void transpose_kernel(
    const float* __restrict__ X, const float* __restrict__ Y,
    _Float16* __restrict__ XT, _Float16* __restrict__ YT) {
  __shared__ _Float16 tile[64][72];
  int zb = blockIdx.z;
  const float* E;
  _Float16* ET;
  if (zb < BB) { E = X + (size_t)zb * NN * DD; ET = XT + (size_t)zb * DD * NN; }
  else { E = Y + (size_t)(zb - BB) * NN * DD; ET = YT + (size_t)(zb - BB) * DD * NN; }
  int n0 = blockIdx.x * 64, d0 = blockIdx.y * 64;
  int t = threadIdx.x;
  int lr = t >> 2, lc = (t & 3) * 16;
#pragma unroll
  for (int k = 0; k < 16; k += 4) {
    float4 v = *(const float4*)(E + (size_t)(n0 + lr) * DD + d0 + lc + k);
    tile[lc + k + 0][lr] = (_Float16)v.x;
    tile[lc + k + 1][lr] = (_Float16)v.y;
    tile[lc + k + 2][lr] = (_Float16)v.z;
    tile[lc + k + 3][lr] = (_Float16)v.w;
  }
  __syncthreads();
#pragma unroll
  for (int k = 0; k < 16; k += 8) {
    h8 o;
#pragma unroll
    for (int j = 0; j < 8; ++j) o[j] = tile[lr][lc + k + j];
    *(h8*)(ET + (size_t)(d0 + lr) * NN + n0 + lc + k) = o;
  }
}

// ---------------- K2: both S-gemms in one dispatch (z = dir*16 + b) ----------
__global__ __launch_bounds__(256) void gemm_a2_kernel(
    const _Float16* __restrict__ Xh, const _Float16* __restrict__ Yh,
    _Float16* __restrict__ A2, _Float16* __restrict__ A2T) {
  const int zb = blockIdx.z;
  const int b = zb & 15;
  const _Float16* Ah = (zb < BB) ? Xh : Yh;
  const _Float16* Bh = (zb < BB) ? Yh : Xh;
  _Float16* Out = (zb < BB) ? A2 : A2T;
  const int I0 = blockIdx.y * 128;
  const int J0 = blockIdx.x * 128;
  const int lane = threadIdx.x & 63;
  const int wave = threadIdx.x >> 6;
  const int m = lane & 15, quad = lane >> 4;
  const _Float16* Abase = Ah + ((size_t)b * NN + I0 + wave * 32) * DD;
  const _Float16* Bbase = Bh + ((size_t)b * NN + J0) * DD;
  f32x4 acc[2][8] = {};
  for (int k0 = 0; k0 < DD; k0 += 32) {
    int koff = k0 + quad * 8;
    h8 a0 = *(const h8*)(Abase + (size_t)m * DD + koff);
    h8 a1 = *(const h8*)(Abase + (size_t)(m + 16) * DD + koff);
#pragma unroll
    for (int t = 0; t < 8; ++t) {
      h8 bf = *(const h8*)(Bbase + (size_t)(t * 16 + m) * DD + koff);
      acc[0][t] = __builtin_amdgcn_mfma_f32_16x16x32_f16(a0, bf, acc[0][t], 0, 0, 0);
      acc[1][t] = __builtin_amdgcn_mfma_f32_16x16x32_f16(a1, bf, acc[1][t], 0, 0, 0);
    }
  }
  _Float16* Ob = Out + ((size_t)b * NN + I0 + wave * 32) * NN + J0;
#pragma unroll
  for (int a = 0; a < 2; ++a)
#pragma unroll
    for (int t = 0; t < 8; ++t)
#pragma unroll
      for (int r = 0; r < 4; ++r) {
        int row = a * 16 + quad * 4 + r;
        int col = t * 16 + m;
        float s = acc[a][t][r];
        float ri = (float)(I0 + wave * 32 + row);
        float ci = (float)(J0 + col);
        Ob[(size_t)row * NN + col] =
            (_Float16)(K_A2 * fmaxf(1.0f - s, 0.0f) - CPOS2 * fabsf(ri - ci));
      }
}

// ---------------- K3: one full sinkhorn iteration, 16 slabs of 64 rows --------
// Partials (m,s fp16 per column per slab) flow between dispatches as plain
// cached traffic (dispatch boundary = coherence). Every block combines the 16
// slab-partials into g at dispatch start (64 KB/block; 16 slabs cuts the
// round-11 redundancy 4x: 64 MB -> 16 MB per iteration).
// grid (16 slabs, BB) x 512 thr; block owns 64 rows of A2.
__global__ __launch_bounds__(512) void sink_iter_kernel(
    const _Float16* __restrict__ A2, const _Float16* __restrict__ partIn,
    _Float16* __restrict__ partOut, float* __restrict__ Fv, int first) {
  __shared__ float lv[NN + NN / 8];
  __shared__ float f_l[64];
  const int b = blockIdx.y;
  const int slab = blockIdx.x;                  // 0..15
  const int t = threadIdx.x, lane = t & 63, wave = t >> 6;   // 8 waves
  // prologue: combine partials -> g (cols 2t, 2t+1); g=0 on first iteration
  if (first) {
    lv[PIDX(2 * t)] = 0.f;
    lv[PIDX(2 * t + 1)] = 0.f;
  } else {
    float M0 = -1e30f, S0 = 0.f, M1 = -1e30f, S1 = 0.f;
    const _Float16* pb = partIn + ((size_t)(b * 16) * NN + 2 * t) * 2;
#pragma unroll 4
    for (int s = 0; s < 16; ++s) {
      hv4 p = *(const hv4*)(pb + (size_t)s * NN * 2);
      float m0 = (float)p[0], v0 = (float)p[1];
      float m1 = (float)p[2], v1 = (float)p[3];
      float Mn0 = fmaxf(M0, m0);
      S0 = S0 * EXP2F(M0 - Mn0) + v0 * EXP2F(m0 - Mn0);
      M0 = Mn0;
      float Mn1 = fmaxf(M1, m1);
      S1 = S1 * EXP2F(M1 - Mn1) + v1 * EXP2F(m1 - Mn1);
      M1 = Mn1;
    }
    lv[PIDX(2 * t)] = BASE2 - (M0 + LOG2F(S0));
    lv[PIDX(2 * t + 1)] = BASE2 - (M1 + LOG2F(S1));
  }
  __syncthreads();
  const int j0 = lane * 8;
  float gv[16];
  ldsVec16p(lv, j0, gv);
  const _Float16* Pb = A2 + (size_t)b * NN * NN;
  const int r0 = slab * 64 + wave * 8;
  // pass A: 8 rows per wave -> f
#pragma unroll
  for (int r = 0; r < 8; ++r) {
    h8 q[2];
    q[0] = *(const h8*)(Pb + (size_t)(r0 + r) * NN + j0);
    q[1] = *(const h8*)(Pb + (size_t)(r0 + r) * NN + 512 + j0);
    float res = lseRow(q, gv);
    if (lane == 0) {
      f_l[wave * 8 + r] = res;
      Fv[b * NN + r0 + r] = res;
    }
  }
  __syncthreads();
  // pass B: partial column-lse over this slab's 64 rows (L2-hot re-read)
  float m0 = -1e30f, s0 = 0.f, m1 = -1e30f, s1 = 0.f;
  const _Float16* cp = Pb + (size_t)(slab * 64) * NN + 2 * t;
#pragma unroll 8
  for (int i = 0; i < 64; ++i) {
    float fi = f_l[i];
    h2 a = *(const h2*)(cp + (size_t)i * NN);
    float x0 = (float)a[0] + fi;
    float x1 = (float)a[1] + fi;
    float mn0 = fmaxf(m0, x0);
    s0 = s0 * EXP2F(m0 - mn0) + EXP2F(x0 - mn0);
    m0 = mn0;
    float mn1 = fmaxf(m1, x1);
    s1 = s1 * EXP2F(m1 - mn1) + EXP2F(x1 - mn1);
    m1 = mn1;
  }
  hv4 o;
  o[0] = (_Float16)m0; o[1] = (_Float16)s0;
  o[2] = (_Float16)m1; o[3] = (_Float16)s1;
  *(hv4*)(partOut + ((size_t)(b * 16 + slab) * NN + 2 * t) * 2) = o;
}

// ---------------- K3b: final g = combine(partials) ----------------
__global__ __launch_bounds__(512) void combine_g_kernel(
    const _Float16* __restrict__ partIn, float* __restrict__ Gf) {
  const int b = blockIdx.x;
  const int t = threadIdx.x;
  float M0 = -1e30f, S0 = 0.f, M1 = -1e30f, S1 = 0.f;
  const _Float16* pb = partIn + ((size_t)(b * 16) * NN + 2 * t) * 2;
#pragma unroll 4
  for (int s = 0; s < 16; ++s) {
    hv4 p = *(const hv4*)(pb + (size_t)s * NN * 2);
    float m0 = (float)p[0], v0 = (float)p[1];
    float m1 = (float)p[2], v1 = (float)p[3];
    float Mn0 = fmaxf(M0, m0);
    S0 = S0 * EXP2F(M0 - Mn0) + v0 * EXP2F(m0 - Mn0);
    M0 = Mn0;
    float Mn1 = fmaxf(M1, m1);
    S1 = S1 * EXP2F(M1 - Mn1) + v1 * EXP2F(m1 - Mn1);
    M1 = Mn1;
  }
  Gf[b * NN + 2 * t] = BASE2 - (M0 + LOG2F(S0));
  Gf[b * NN + 2 * t + 1] = BASE2 - (M1 + LOG2F(S1));
}

// ---------------- K4: marginals (row dir only) + c = 2^BASE2 exactly ----------
// After the g-update, column sums are exactly 2^BASE2 by the Sinkhorn identity
// (c_j = sum_i exp2(a2+f+g_j) = 2^(g_j + lse-col) = 2^BASE2) — same identity
// the reference's math satisfies — so the column pass is deleted.
__global__ __launch_bounds__(512) void marginals_kernel(
    const _Float16* __restrict__ A2, const float* __restrict__ F,
    const float* __restrict__ G, float* __restrict__ rOut,
    float* __restrict__ cOut, float* __restrict__ Lrow) {
  __shared__ float lv[NN + NN / 8];
  const int b = blockIdx.y, sub = blockIdx.x;  // sub 0..7
  const int t = threadIdx.x, lane = t & 63, wave = t >> 6;
  float2 v = *(const float2*)(G + b * NN + 2 * t);
  lv[PIDX(2 * t + 0)] = v.x;
  lv[PIDX(2 * t + 1)] = v.y;
  __syncthreads();
  const int j0 = lane * 8;
  float gv[16];
  ldsVec16p(lv, j0, gv);
  const _Float16* Pb = A2 + (size_t)b * NN * NN;
  const int wg = sub * 8 + wave;               // 0..63
  for (int s = 0; s < 16; ++s) {
    int i = wg + s * 64;
    float fi = F[b * NN + i];
    const _Float16* row = Pb + (size_t)i * NN;
    h8 qa = *(const h8*)(row + j0);
    h8 qb = *(const h8*)(row + 512 + j0);
    float fr = (float)i;
    float sr = 0.f, sl = 0.f;
#pragma unroll
    for (int k = 0; k < 8; ++k) {
      float a2a = (float)qa[k];
      float a2b = (float)qb[k];
      float Ta = EXP2F(a2a + fi + gv[k]);
      float Tb = EXP2F(a2b + fi + gv[8 + k]);
      sr += Ta + Tb;
      float ca = a2a + CPOS2 * fabsf(fr - (float)(j0 + k));
      float cb = a2b + CPOS2 * fabsf(fr - (float)(512 + j0 + k));
      sl = fmaf(Ta, ca, sl);
      sl = fmaf(Tb, cb, sl);
    }
    sr = waveReduceSum(sr);
    sl = waveReduceSum(sl);
    if (lane == 0) {
      rOut[b * NN + i] = sr;
      cOut[b * NN + i] = EXP2F(BASE2);
      Lrow[b * NN + i] = -C1 * sl;
    }
  }
}

// ---------------- K6: MFMA bary, both directions in one dispatch (z) --------
__global__ __launch_bounds__(256) void bary_mfma_kernel(
    const _Float16* __restrict__ A2, const _Float16* __restrict__ A2T,
    const float* __restrict__ F, const float* __restrict__ G,
    const float* __restrict__ r, const float* __restrict__ c,
    const _Float16* __restrict__ XT, const _Float16* __restrict__ YT,
    const float* __restrict__ X, const float* __restrict__ Y,
    float* __restrict__ baryA, float* __restrict__ baryB) {
  __shared__ float gl[NN];
  __shared__ float red[4];
  const int z = blockIdx.z;
  const _Float16* P = z ? A2T : A2;
  const float* rowv = z ? G : F;
  const float* colv = z ? F : G;
  const float* denom = z ? c : r;
  const _Float16* EmbT = z ? XT : YT;
  const float* Ref = z ? Y : X;
  float* baryAcc = z ? baryB : baryA;
  const int b = blockIdx.y;
  const int I0 = blockIdx.x * 64;
  const int t = threadIdx.x, lane = t & 63, wave = t >> 6;
  const int m = lane & 15, quad = lane >> 4;
  gl[t] = colv[b * NN + t];
  gl[t + 256] = colv[b * NN + t + 256];
  gl[t + 512] = colv[b * NN + t + 512];
  gl[t + 768] = colv[b * NN + t + 768];
  __syncthreads();
  const int row = I0 + wave * 16 + m;
  const float fi = rowv[b * NN + row] + 10.0f;        // fold 2^10 scale
  const _Float16* Pr = P + (size_t)b * NN * NN + (size_t)row * NN + quad * 8;
  const _Float16* ET = EmbT + (size_t)b * DD * NN;
  f32x4 acc[16];
#pragma unroll
  for (int i = 0; i < 16; ++i) acc[i] = (f32x4){0.f, 0.f, 0.f, 0.f};
  for (int kc = 0; kc < NN; kc += 32) {
    h8 a2v = *(const h8*)(Pr + kc);
    float4 g0 = *(const float4*)&gl[kc + quad * 8];
    float4 g1 = *(const float4*)&gl[kc + quad * 8 + 4];
    h8 af;
    af[0] = (_Float16)EXP2F((float)a2v[0] + fi + g0.x);
    af[1] = (_Float16)EXP2F((float)a2v[1] + fi + g0.y);
    af[2] = (_Float16)EXP2F((float)a2v[2] + fi + g0.z);
    af[3] = (_Float16)EXP2F((float)a2v[3] + fi + g0.w);
    af[4] = (_Float16)EXP2F((float)a2v[4] + fi + g1.x);
    af[5] = (_Float16)EXP2F((float)a2v[5] + fi + g1.y);
    af[6] = (_Float16)EXP2F((float)a2v[6] + fi + g1.z);
    af[7] = (_Float16)EXP2F((float)a2v[7] + fi + g1.w);
#pragma unroll
    for (int nt = 0; nt < 16; ++nt) {
      h8 bf = *(const h8*)(ET + (size_t)(nt * 16 + m) * NN + kc + quad * 8);
      acc[nt] = __builtin_amdgcn_mfma_f32_16x16x32_f16(af, bf, acc[nt], 0, 0, 0);
    }
  }
  float vs = 0.f;
#pragma unroll
  for (int r4 = 0; r4 < 4; ++r4) {
    int iabs = I0 + wave * 16 + quad * 4 + r4;
    float inv = 1.0f / (1024.0f * (denom[b * NN + iabs] + 1e-8f));
    const float* Rrow = Ref + ((size_t)b * NN + iabs) * DD;
#pragma unroll
    for (int nt = 0; nt < 16; ++nt) {
      int d = nt * 16 + m;
      float val = Rrow[d] - acc[nt][r4] * inv;
      vs = fmaf(val, val, vs);
    }
  }
  vs = waveReduceSum(vs);
  if (lane == 0) red[wave] = vs;
  __syncthreads();
  if (t == 0) atomicAdd(baryAcc + b, red[0] + red[1] + red[2] + red[3]);
}

// ---------------- K7: partial global sums X*r, Y*c ----------------
__global__ __launch_bounds__(256) void xg_kernel(
    const float* __restrict__ X, const float* __restrict__ Y,
    const float* __restrict__ r, const float* __restrict__ c,
    float* __restrict__ xgp, float* __restrict__ ygp) {
  const int b = blockIdx.y, seg = blockIdx.x, d = threadIdx.x;
  float ax = 0.f, ay = 0.f;
  for (int ii = 0; ii < 256; ++ii) {
    int i = seg * 256 + ii;
    float rvv = r[b * NN + i];
    float cvv = c[b * NN + i];
    ax = fmaf(X[((size_t)b * NN + i) * DD + d], rvv, ax);
    ay = fmaf(Y[((size_t)b * NN + i) * DD + d], cvv, ay);
  }
  xgp[(size_t)(b * 4 + seg) * DD + d] = ax;
  ygp[(size_t)(b * 4 + seg) * DD + d] = ay;
}

// ---------------- K8: per-batch finalize ----------------
__global__ __launch_bounds__(256) void finalize_batch(
    const float* __restrict__ r, const float* __restrict__ c,
    const float* __restrict__ Lrow, const float* __restrict__ xgp,
    const float* __restrict__ ygp, const float* __restrict__ baryA,
    const float* __restrict__ baryB, float* __restrict__ lossArr) {
  const int b = blockIdx.x;
  const int t = threadIdx.x;
  __shared__ float sd[256];
  auto bsum = [&](float v) -> float {
    sd[t] = v; __syncthreads();
    for (int o = 128; o; o >>= 1) { if (t < o) sd[t] += sd[t + o]; __syncthreads(); }
    float res = sd[0]; __syncthreads();
    return res;
  };
  float vr = 0.f, vc = 0.f, vl = 0.f;
  for (int k = 0; k < 4; ++k) {
    int i = t + 256 * k;
    vr += r[b * NN + i];
    vc += c[b * NN + i];
    vl += Lrow[b * NN + i];
  }
  float sumR = bsum(vr);
  float sumC = bsum(vc);
  float Lmain = bsum(vl);
  float xg = (xgp[(size_t)(b * 4 + 0) * DD + t] + xgp[(size_t)(b * 4 + 1) * DD + t] +
              xgp[(size_t)(b * 4 + 2) * DD + t] + xgp[(size_t)(b * 4 + 3) * DD + t]) /
             (sumR + 1e-8f);
  float yg = (ygp[(size_t)(b * 4 + 0) * DD + t] + ygp[(size_t)(b * 4 + 1) * DD + t] +
              ygp[(size_t)(b * 4 + 2) * DD + t] + ygp[(size_t)(b * 4 + 3) * DD + t]) /
             (sumC + 1e-8f);
  float nx = bsum(xg * xg);
  float ny = bsum(yg * yg);
  float dt = bsum(xg * yg);
  if (t == 0) {
    float mx = fmaxf(sqrtf(nx), 1e-12f);
    float my = fmaxf(sqrtf(ny), 1e-12f);
    float cosv = dt / (mx * my);
    float lb = (baryA[b] + baryB[b]) * (1.0f / ((float)NN * (float)DD));
    lossArr[b] = Lmain + 0.5f * lb + 0.2f * (1.0f - cosv);
  }
}

__global__ void final_mean(const float* __restrict__ lossArr, float* __restrict__ out) {
  int t = threadIdx.x;
  float v = (t < BB) ? lossArr[t] : 0.f;
  v = waveReduceSum(v);
  if (t == 0) out[0] = v * (1.0f / BB);
}

// ---------------- launch ----------------
extern "C" void kernel_launch(void* const* d_in, const int* in_sizes, int n_in,
                              void* d_out, int out_size, void* d_ws, size_t ws_size,
                              hipStream_t stream) {
  const float* X = (const float*)d_in[0];
  const float* Y = (const float*)d_in[1];
  float* out = (float*)d_out;
  char* ws = (char*)d_ws;
  size_t off = 0;
  auto take = [&](size_t bytes) -> char* {
    char* p = ws + off;
    off = (off + bytes + 255) & ~(size_t)255;
    return p;
  };
  _Float16* Xh = (_Float16*)take((size_t)BB * NN * DD * 2);
  _Float16* Yh = (_Float16*)take((size_t)BB * NN * DD * 2);
  _Float16* XT_h = (_Float16*)take((size_t)BB * DD * NN * 2);
  _Float16* YT_h = (_Float16*)take((size_t)BB * DD * NN * 2);
  _Float16* A2 = (_Float16*)take((size_t)BB * NN * NN * 2);
  _Float16* A2T = (_Float16*)take((size_t)BB * NN * NN * 2);
  _Float16* P0 = (_Float16*)take((size_t)BB * 16 * NN * 2 * 2);  // (m,s) fp16, 1 MB
  _Float16* P1 = (_Float16*)take((size_t)BB * 16 * NN * 2 * 2);
  size_t zstart = off;
  float* baryA = (float*)take(64);
  float* baryB = (float*)take(64);
  size_t zlen = off - zstart;
  float* Fv = (float*)take((size_t)BB * NN * 4);
  float* Gf = (float*)take((size_t)BB * NN * 4);
  float* r = (float*)take((size_t)BB * NN * 4);
  float* c = (float*)take((size_t)BB * NN * 4);
  float* Lrow = (float*)take((size_t)BB * NN * 4);
  float* xgp = (float*)take((size_t)BB * 4 * DD * 4);
  float* ygp = (float*)take((size_t)BB * 4 * DD * 4);
  float* lossArr = (float*)take(64);
  (void)in_sizes; (void)n_in; (void)out_size; (void)ws_size;

  hipMemsetAsync(ws + zstart, 0, zlen, stream);

  normalize_kernel<<<dim3(2 * BB * NN / 4), dim3(256), 0, stream>>>(X, Y, Xh, Yh);
  transpose_kernel<<<dim3(NN / 64, DD / 64, 2 * BB), dim3(256), 0, stream>>>(X, Y, XT_h,
                                                                             YT_h);
  gemm_a2_kernel<<<dim3(NN / 128, NN / 128, 2 * BB), dim3(256), 0, stream>>>(Xh, Yh, A2,
                                                                             A2T);
  _Float16* pbuf[2] = {P0, P1};
  for (int it = 0; it < 50; ++it) {
    sink_iter_kernel<<<dim3(16, BB), dim3(512), 0, stream>>>(
        A2, pbuf[(it + 1) & 1], pbuf[it & 1], Fv, it == 0 ? 1 : 0);
  }
  combine_g_kernel<<<dim3(BB), dim3(512), 0, stream>>>(pbuf[1], Gf);  // 49&1 == 1
  marginals_kernel<<<dim3(8, BB), dim3(512), 0, stream>>>(A2, Fv, Gf, r, c, Lrow);
  bary_mfma_kernel<<<dim3(NN / 64, BB, 2), dim3(256), 0, stream>>>(
      A2, A2T, Fv, Gf, r, c, XT_h, YT_h, X, Y, baryA, baryB);
  xg_kernel<<<dim3(4, BB), dim3(256), 0, stream>>>(X, Y, r, c, xgp, ygp);
  finalize_batch<<<dim3(BB), dim3(256), 0, stream>>>(r, c, Lrow, xgp, ygp, baryA, baryB,
                                                     lossArr);
  final_mean<<<dim3(1), dim3(64), 0, stream>>>(lossArr, out);
}